// Round 7
// baseline (201.036 us; speedup 1.0000x reference)
//
#include <hip/hip_runtime.h>
#include <math.h>

// v7: MEASUREMENT ROUND -- v6 kernel byte-identical, launched TWICE.
//
// Rationale: since r5 the kernel is below the top-5 counter cutoff (~60us,
// the harness's own 400MB fills), so its true duration is unobservable; the
// "dur_us - 113us overhead" inference was calibrated only on r2-r4 and may
// be wrong. Double-launch gives dur7 = C + 2*K vs r6's C + K = 168.7us,
// so K = dur7 - 168.7 with no new assumptions. Second launch is idempotent
// (same inputs -> same outputs, out overwritten), deterministic, and
// graph-capture legal. Branch plan: K~55 -> attack latency serialization
// (LDS bank padding: sample stride 100 words == 4*sl mod 32 is 4-way
// aliased; ds prefetch pipelining). K<~25 -> near memory+overhead floor.

typedef float v2f __attribute__((ext_vector_type(2)));

#define SREAD(x) __int_as_float(__builtin_amdgcn_readfirstlane(__float_as_int(x)))

__device__ __forceinline__ float dpp_swap1_f(float x) {
    return __int_as_float(__builtin_amdgcn_mov_dpp(__float_as_int(x), 0xB1, 0xF, 0xF, true));
}
__device__ __forceinline__ unsigned dpp_swap1_u(unsigned x) {
    return (unsigned)__builtin_amdgcn_mov_dpp((int)x, 0xB1, 0xF, 0xF, true);
}

__device__ __forceinline__ void gload16(const float* g, float* l) {
    __builtin_amdgcn_global_load_lds(
        (const __attribute__((address_space(1))) void*)g,
        (__attribute__((address_space(3))) void*)l, 16, 0, 0);
}
__device__ __forceinline__ void gload4(const float* g, float* l) {
    __builtin_amdgcn_global_load_lds(
        (const __attribute__((address_space(1))) void*)g,
        (__attribute__((address_space(3))) void*)l, 4, 0, 0);
}

__global__ __launch_bounds__(256) void CNN2D_37495064494620_kernel(
    const float* __restrict__ v,
    const float* __restrict__ cw,   // [4,1,3,3]
    const float* __restrict__ cb,   // [4]
    const float* __restrict__ dw,   // [4,1,2,2]
    const float* __restrict__ db,   // [1]
    float* __restrict__ out,        // [2*B]
    int B)
{
    const int tid = threadIdx.x;          // 256 threads = 4 waves
    const int q   = tid & 1;              // conv-row parity / kl-pair owner
    const int sl  = tid >> 1;             // local sample 0..127

    __shared__ __align__(16) float sm[12800];   // 128 samples x 100 = 51.2 KB

    // Coalesced stage: 12 x (256 lanes x 16B) + 2 x (256 lanes x 4B).
    const float* gbase = v + (size_t)blockIdx.x * 12800;
    const int widx = tid >> 6;
    #pragma unroll
    for (int k = 0; k < 12; ++k)
        gload16(gbase + k * 1024 + tid * 4, &sm[k * 1024 + widx * 256]);
    #pragma unroll
    for (int k = 0; k < 2; ++k)
        gload4(gbase + 12288 + k * 256 + tid, &sm[12288 + k * 256 + widx * 64]);

    // Wave-uniform weights -> SGPRs; conv weights packed over filter pairs.
    float Wf[4][9];
    #pragma unroll
    for (int f = 0; f < 4; ++f)
        #pragma unroll
        for (int t = 0; t < 9; ++t)
            Wf[f][t] = SREAD(cw[f * 9 + t]);
    v2f W2[9][2];
    #pragma unroll
    for (int t = 0; t < 9; ++t) {
        W2[t][0] = (v2f){Wf[0][t], Wf[1][t]};
        W2[t][1] = (v2f){Wf[2][t], Wf[3][t]};
    }
    const v2f Cb2[2] = { (v2f){SREAD(cb[0]), SREAD(cb[1])},
                         (v2f){SREAD(cb[2]), SREAD(cb[3])} };
    float Dw[4][4];
    #pragma unroll
    for (int f = 0; f < 4; ++f)
        #pragma unroll
        for (int t = 0; t < 4; ++t)
            Dw[f][t] = SREAD(dw[f * 4 + t]);
    const float Db = SREAD(db[0]);

    // This lane's deconv kl-pair weights: kl = 2q, 2q+1.
    v2f Dq[4];
    #pragma unroll
    for (int f = 0; f < 4; ++f)
        Dq[f] = (v2f){ q ? Dw[f][2] : Dw[f][0], q ? Dw[f][3] : Dw[f][1] };

    __syncthreads();   // drain staging

    const float* my = sm + sl * 100;

    unsigned sbits = 0u;
    float l2 = 0.0f;

    #pragma unroll
    for (int i = 0; i < 5; ++i) {
        const int r1 = 2 * i + q;
        const int r0 = (i == 0) ? (q ? 0 : 9) : (2 * i - 1 + q);
        const int r2 = (i == 4) ? (q ? 0 : 9) : (2 * i + 1 + q);

        float R[3][10];
        #pragma unroll
        for (int t = 0; t < 5; ++t) {
            float2 x0 = *(const float2*)(my + r0 * 10 + 2 * t);
            float2 x1 = *(const float2*)(my + r1 * 10 + 2 * t);
            float2 x2 = *(const float2*)(my + r2 * 10 + 2 * t);
            R[0][2 * t] = x0.x; R[0][2 * t + 1] = x0.y;
            R[1][2 * t] = x1.x; R[1][2 * t + 1] = x1.y;
            R[2][2 * t] = x2.x; R[2][2 * t + 1] = x2.y;
        }

        #pragma unroll
        for (int j = 0; j < 5; ++j) {
            v2f a0[2] = {Cb2[0], Cb2[1]};
            v2f a1[2] = {Cb2[0], Cb2[1]};
            #pragma unroll
            for (int kr = 0; kr < 3; ++kr) {
                #pragma unroll
                for (int kc = 0; kc < 3; ++kc) {
                    const int cc0 = (2 * j + kc + 9) % 10;
                    const int cc1 = (2 * j + 1 + kc + 9) % 10;
                    const int t = kr * 3 + kc;
                    const v2f x0 = (v2f){R[kr][cc0], R[kr][cc0]};
                    const v2f x1 = (v2f){R[kr][cc1], R[kr][cc1]};
                    a0[0] = __builtin_elementwise_fma(x0, W2[t][0], a0[0]);
                    a0[1] = __builtin_elementwise_fma(x0, W2[t][1], a0[1]);
                    a1[0] = __builtin_elementwise_fma(x1, W2[t][0], a1[0]);
                    a1[1] = __builtin_elementwise_fma(x1, W2[t][1], a1[1]);
                }
            }
            const v2f m0 = __builtin_elementwise_max(a0[0], a1[0]);
            const v2f m1 = __builtin_elementwise_max(a0[1], a1[1]);
            float P[4];
            P[0] = fmaxf(m0.x, dpp_swap1_f(m0.x));
            P[1] = fmaxf(m0.y, dpp_swap1_f(m0.y));
            P[2] = fmaxf(m1.x, dpp_swap1_f(m1.x));
            P[3] = fmaxf(m1.y, dpp_swap1_f(m1.y));

            v2f z2 = (v2f){Db, Db};
            #pragma unroll
            for (int f = 0; f < 4; ++f) {
                const v2f pf = (v2f){P[f], P[f]};
                z2 = __builtin_elementwise_fma(pf, Dq[f], z2);
            }
            sbits ^= __float_as_uint(z2.x) ^ __float_as_uint(z2.y);
            l2 += __log2f(fabsf(z2.x * z2.y));
        }
    }

    l2 = l2 + dpp_swap1_f(l2);
    sbits = sbits ^ dpp_swap1_u(sbits);

    const int s = blockIdx.x * 128 + sl;
    const float val = q ? (l2 * 0.69314718055994531f)
                        : ((sbits & 0x80000000u) ? -1.0f : 1.0f);
    out[q * B + s] = val;
}

extern "C" void kernel_launch(void* const* d_in, const int* in_sizes, int n_in,
                              void* d_out, int out_size, void* d_ws, size_t ws_size,
                              hipStream_t stream) {
    const float* v  = (const float*)d_in[0];
    const float* cw = (const float*)d_in[1];
    const float* cb = (const float*)d_in[2];
    const float* dw = (const float*)d_in[3];
    const float* db = (const float*)d_in[4];
    float* out = (float*)d_out;

    const int B = in_sizes[0] / 100;       // 262144
    const int grid = B / 128;              // 128 samples per 256-thread block

    // Double launch: identical work, idempotent output. dur = C + 2K, and
    // r6 gave C + K = 168.7us -> K = dur - 168.7.
    CNN2D_37495064494620_kernel<<<grid, 256, 0, stream>>>(v, cw, cb, dw, db, out, B);
    CNN2D_37495064494620_kernel<<<grid, 256, 0, stream>>>(v, cw, cb, dw, db, out, B);
}

// Round 8
// 183.491 us; speedup vs baseline: 1.0956x; 1.0956x over previous
//
#include <hip/hip_runtime.h>
#include <math.h>

// v8: persistent blocks + register-double-buffered staging.
//
// Measured (r6/r7 launch algebra): C=114us harness, K_cold=55us, K_hot=32us.
// ~23us of K_cold is un-overlapped refetch of v (L3 evicted by harness
// poison fills; FETCH~51MB/launch). Old structure: stage-burst -> barrier
// (vmcnt(0) = full latency exposed) -> compute, 8x per CU. New: persistent
// 128-thr blocks x 4 tiles; while computing tile n, the next tile's 25
// coalesced float2 loads sit in VGPRs (plain global loads don't drain at
// barriers -- only their use waits), so HBM latency hides under ~1.4us of
// compute. Compute = v6's proven scalar body + row-reuse (50 ds_read/tile).

#define SREAD(x) __int_as_float(__builtin_amdgcn_readfirstlane(__float_as_int(x)))

__device__ __forceinline__ float dpp_swap1_f(float x) {
    return __int_as_float(__builtin_amdgcn_mov_dpp(__float_as_int(x), 0xB1, 0xF, 0xF, true));
}
__device__ __forceinline__ unsigned dpp_swap1_u(unsigned x) {
    return (unsigned)__builtin_amdgcn_mov_dpp((int)x, 0xB1, 0xF, 0xF, true);
}

__device__ __forceinline__ void ldrow(float (&R)[10], const float* p) {
    #pragma unroll
    for (int t = 0; t < 5; ++t) {
        float2 x = *(const float2*)(p + 2 * t);
        R[2 * t] = x.x; R[2 * t + 1] = x.y;
    }
}

// One pooled row: X = input row r1-1, Y = r1 (this lane's conv row), Z = r1+1.
__device__ __forceinline__ void step(
    const float (&X)[10], const float (&Y)[10], const float (&Z)[10],
    const float (&W)[4][9], const float (&Cb)[4],
    const float (&Dq0)[4], const float (&Dq1)[4], const float Db,
    unsigned& sbits, float& l2)
{
    #pragma unroll
    for (int j = 0; j < 5; ++j) {
        float a[4], b[4];
        #pragma unroll
        for (int f = 0; f < 4; ++f) { a[f] = Cb[f]; b[f] = Cb[f]; }
        #pragma unroll
        for (int kc = 0; kc < 3; ++kc) {
            const int c0 = (2 * j + kc + 9) % 10;       // compile-time
            const int c1 = (2 * j + 1 + kc + 9) % 10;
            #pragma unroll
            for (int f = 0; f < 4; ++f) {
                a[f] = fmaf(X[c0], W[f][kc], a[f]);
                b[f] = fmaf(X[c1], W[f][kc], b[f]);
            }
            #pragma unroll
            for (int f = 0; f < 4; ++f) {
                a[f] = fmaf(Y[c0], W[f][3 + kc], a[f]);
                b[f] = fmaf(Y[c1], W[f][3 + kc], b[f]);
            }
            #pragma unroll
            for (int f = 0; f < 4; ++f) {
                a[f] = fmaf(Z[c0], W[f][6 + kc], a[f]);
                b[f] = fmaf(Z[c1], W[f][6 + kc], b[f]);
            }
        }
        float P[4];
        #pragma unroll
        for (int f = 0; f < 4; ++f) {
            const float m = fmaxf(a[f], b[f]);          // dc-merge
            P[f] = fmaxf(m, dpp_swap1_f(m));            // row-pool via DPP
        }
        float z0 = Db, z1 = Db;                          // this lane's kl pair
        #pragma unroll
        for (int f = 0; f < 4; ++f) {
            z0 = fmaf(P[f], Dq0[f], z0);
            z1 = fmaf(P[f], Dq1[f], z1);
        }
        sbits ^= __float_as_uint(z0) ^ __float_as_uint(z1);
        l2 += __log2f(fabsf(z0 * z1));
    }
}

__global__ __launch_bounds__(128) void CNN2D_37495064494620_kernel(
    const float* __restrict__ v,
    const float* __restrict__ cw,   // [4,1,3,3]
    const float* __restrict__ cb,   // [4]
    const float* __restrict__ dw,   // [4,1,2,2]
    const float* __restrict__ db,   // [1]
    float* __restrict__ out,        // [2*B]
    int B)
{
    const int tid = threadIdx.x;          // 128 threads = 2 waves
    const int q   = tid & 1;              // conv-row parity / kl-pair owner
    const int sl  = tid >> 1;             // local sample 0..63

    __shared__ __align__(16) float sm[6400];   // one 64-sample tile = 25.6 KB

    // Wave-uniform weights -> SGPRs.
    float W[4][9];
    #pragma unroll
    for (int f = 0; f < 4; ++f)
        #pragma unroll
        for (int t = 0; t < 9; ++t)
            W[f][t] = SREAD(cw[f * 9 + t]);
    float Cb[4];
    #pragma unroll
    for (int f = 0; f < 4; ++f) Cb[f] = SREAD(cb[f]);
    float Dw[4][4];
    #pragma unroll
    for (int f = 0; f < 4; ++f)
        #pragma unroll
        for (int t = 0; t < 4; ++t)
            Dw[f][t] = SREAD(dw[f * 4 + t]);
    const float Db = SREAD(db[0]);
    float Dq0[4], Dq1[4];                 // this lane's deconv kl pair (VGPR)
    #pragma unroll
    for (int f = 0; f < 4; ++f) {
        Dq0[f] = q ? Dw[f][2] : Dw[f][0];
        Dq1[f] = q ? Dw[f][3] : Dw[f][1];
    }

    // Prefetch tile 0 into registers (coalesced: 25 x 128 lanes x 8B).
    float2 PF[25];
    {
        const float2* g = (const float2*)(v + (size_t)blockIdx.x * 4 * 6400);
        #pragma unroll
        for (int k = 0; k < 25; ++k) PF[k] = g[k * 128 + tid];
    }

    #pragma clang loop unroll(disable)
    for (int n = 0; n < 4; ++n) {
        const int t = blockIdx.x * 4 + n;

        __syncthreads();   // prior tile's compute done -> safe to overwrite sm

        // Registers -> LDS (layout identical to global: sm linear = tile linear).
        #pragma unroll
        for (int k = 0; k < 25; ++k)
            *(float2*)&sm[k * 256 + tid * 2] = PF[k];

        // Issue next tile's global loads now; first USE is next iteration's
        // ds_write, ~1.4us away -> HBM latency hidden under compute.
        if (n < 3) {
            const float2* g = (const float2*)(v + (size_t)(t + 1) * 6400);
            #pragma unroll
            for (int k = 0; k < 25; ++k) PF[k] = g[k * 128 + tid];
        }

        __syncthreads();   // publish sm

        const float* my = sm + sl * 100;
        unsigned sbits = 0u;
        float l2 = 0.0f;

        // Rows this lane needs (parity q): A=(q?0:9), B=q, C=q+1, D..J=2+q..8+q.
        // Windows: i=0:(A,B,C) 1:(C,D,E) 2:(E,F,G) 3:(G,H,I) 4:(I,J,A).
        float A[10], Br[10], C[10], D[10], E[10], Fr[10], G[10], H[10], I[10], J[10];
        ldrow(A,  my + 10 * (q ? 0 : 9));
        ldrow(Br, my + 10 * q);
        ldrow(C,  my + 10 * (q + 1));
        step(A, Br, C, W, Cb, Dq0, Dq1, Db, sbits, l2);          // i=0
        ldrow(D,  my + 10 * (2 + q));
        ldrow(E,  my + 10 * (3 + q));
        step(C, D, E, W, Cb, Dq0, Dq1, Db, sbits, l2);           // i=1
        ldrow(Fr, my + 10 * (4 + q));
        ldrow(G,  my + 10 * (5 + q));
        step(E, Fr, G, W, Cb, Dq0, Dq1, Db, sbits, l2);          // i=2
        ldrow(H,  my + 10 * (6 + q));
        ldrow(I,  my + 10 * (7 + q));
        step(G, H, I, W, Cb, Dq0, Dq1, Db, sbits, l2);           // i=3
        ldrow(J,  my + 10 * (8 + q));
        step(I, J, A, W, Cb, Dq0, Dq1, Db, sbits, l2);           // i=4 (wraps to A)

        // Combine partials across the lane pair; write both outputs.
        const float l2t = l2 + dpp_swap1_f(l2);
        const unsigned st = sbits ^ dpp_swap1_u(sbits);
        const int s = t * 64 + sl;
        const float val = q ? (l2t * 0.69314718055994531f)
                            : ((st & 0x80000000u) ? -1.0f : 1.0f);
        out[q * B + s] = val;
    }
}

extern "C" void kernel_launch(void* const* d_in, const int* in_sizes, int n_in,
                              void* d_out, int out_size, void* d_ws, size_t ws_size,
                              hipStream_t stream) {
    const float* v  = (const float*)d_in[0];
    const float* cw = (const float*)d_in[1];
    const float* cb = (const float*)d_in[2];
    const float* dw = (const float*)d_in[3];
    const float* db = (const float*)d_in[4];
    float* out = (float*)d_out;

    const int B = in_sizes[0] / 100;       // 262144
    const int grid = B / 256;              // 1024 blocks x 4 tiles x 64 samples
    CNN2D_37495064494620_kernel<<<grid, 128, 0, stream>>>(v, cw, cb, dw, db, out, B);
}